// Round 14
// baseline (137.919 us; speedup 1.0000x reference)
//
#include <hip/hip_runtime.h>

using u32 = unsigned int;
using u16 = unsigned short;

typedef __attribute__((ext_vector_type(8)))  __bf16 bf16x8;
typedef __attribute__((ext_vector_type(16))) float  f32x16;
typedef __attribute__((ext_vector_type(4)))  float  f32x4;
typedef __attribute__((ext_vector_type(4)))  int    i32x4;

__device__ __forceinline__ u32 f2bf(float f){
  u32 u = __float_as_uint(f);
  return (u + 0x7FFFu + ((u >> 16) & 1u)) >> 16;
}
__device__ __forceinline__ u32 pack2bf(float lo, float hi){
  return f2bf(lo) | (f2bf(hi) << 16);
}
__device__ __forceinline__ float bfu2f(u32 us){ return __uint_as_float(us << 16); }
__device__ __forceinline__ float lrelu(float x){ return x > 0.f ? x : 0.01f * x; }

// ---------- K0: weight [512][256] f32 -> wT [256][512] bf16 ----------
__global__ void k0_wt(const float* __restrict__ w, u16* __restrict__ wT){
  int u = blockIdx.x * 256 + threadIdx.x;
  int k = u >> 8, n = u & 255;
  wT[(size_t)n * 512 + k] = (u16)f2bf(w[(size_t)k * 256 + n]);
}

// ---------- K1: out = x@W -> outF (MFMA-frag layout) + v0/v1 + p(bf16) ----------
__global__ __launch_bounds__(512, 2) void k1_gemm(const float* __restrict__ x,
    const u16* __restrict__ wT, const float* __restrict__ av, u16* __restrict__ outF,
    float* __restrict__ v0, float* __restrict__ v1, u16* __restrict__ pbf){
  __shared__ float tb[8][32][36];
  __shared__ float afl[512];
  __shared__ float sred[2][32][17];
  __shared__ float srw[2][32];
  const int i0 = blockIdx.x * 32;
  const int tid = threadIdx.x;
  const int lane = tid & 63, wv = tid >> 6;
  const int r = lane & 31, h = lane >> 5;
  const float* xp = x + (size_t)(i0 + r) * 512 + h * 8;
  const u16*   bp = wT + (size_t)(wv * 32 + r) * 512 + h * 8;
  f32x16 acc = {};
  for (int s = 0; s < 32; ++s){
    f32x4 a0 = *(const f32x4*)xp;
    f32x4 a1 = *(const f32x4*)(xp + 4);
    i32x4 pk = { (int)pack2bf(a0[0], a0[1]), (int)pack2bf(a0[2], a0[3]),
                 (int)pack2bf(a1[0], a1[1]), (int)pack2bf(a1[2], a1[3]) };
    bf16x8 af = __builtin_bit_cast(bf16x8, pk);
    bf16x8 bf = *(const bf16x8*)bp;
    acc = __builtin_amdgcn_mfma_f32_32x32x16_bf16(af, bf, acc, 0, 0, 0);
    xp += 16; bp += 16;
  }
  #pragma unroll
  for (int re = 0; re < 16; ++re){
    int rr = (re & 3) + 8 * (re >> 2) + 4 * h;
    tb[wv][r][rr] = acc[re];
  }
  afl[tid] = av[tid];
  __syncthreads();
  {
    const int n2 = lane >> 1, ic = (lane & 1) * 16;
    const float* tp = &tb[wv][n2][ic];
    i32x4 w0 = { (int)pack2bf(tp[0],tp[1]),   (int)pack2bf(tp[2],tp[3]),
                 (int)pack2bf(tp[4],tp[5]),   (int)pack2bf(tp[6],tp[7]) };
    i32x4 w1 = { (int)pack2bf(tp[8],tp[9]),   (int)pack2bf(tp[10],tp[11]),
                 (int)pack2bf(tp[12],tp[13]), (int)pack2bf(tp[14],tp[15]) };
    const int n = wv * 32 + n2;
    const int k16 = (i0 + ic) >> 4;
    u16* op = outF + ((size_t)k16 * 256 + n) * 16;
    *(i32x4*)op = w0;
    *((i32x4*)op + 1) = w1;
  }
  const int row = tid & 31, g = tid >> 5;
  const int w8 = g >> 1, fh = (g & 1) * 16;
  float a1c = 0.f, a2c = 0.f;
  #pragma unroll
  for (int f = 0; f < 16; ++f){
    float tv = tb[w8][fh + f][row];
    a1c = fmaf(tv, afl[w8 * 32 + fh + f], a1c);
    a2c = fmaf(tv, afl[256 + w8 * 32 + fh + f], a2c);
  }
  sred[0][row][g] = a1c; sred[1][row][g] = a2c;
  __syncthreads();
  if (tid < 64){
    int which = tid >> 5, r2 = tid & 31;
    float s = 0.f;
    #pragma unroll
    for (int g2 = 0; g2 < 16; ++g2) s += sred[which][r2][g2];
    srw[which][r2] = s;
  }
  __syncthreads();
  if (tid < 16){
    int k = (i0 >> 1) + tid;
    float sa  = srw[0][2*tid],   sb  = srw[1][2*tid];
    float sa1 = srw[0][2*tid+1], sb1 = srw[1][2*tid+1];
    v0[k] = lrelu(sa + sb);
    v1[k] = lrelu(sa1 + sb1);
    float w = lrelu(sa + sb1);
    pbf[k] = (u16)f2bf(__expf(w));
  }
}

// ---------- K2BM: adj int32 -> bitmask (8 MB). Pure stream, no barriers. ----------
// One wave per row. Lane l packs 32 consecutive int32 (128 B local segment) into one
// u32; wave covers 2048 K per iteration (8 KB contiguous footprint, L1-absorbed).
__global__ __launch_bounds__(256, 2) void k2bm(const int* __restrict__ adj,
                                               u32* __restrict__ bm){
  const int row = blockIdx.x * 4 + (threadIdx.x >> 6);
  const int l = threadIdx.x & 63;
  const int* ap = adj + (size_t)row * 8192 + l * 32;
  u32* bp = bm + (size_t)row * 256 + l;
  #pragma unroll
  for (int it = 0; it < 4; ++it){
    i32x4 v[8];
    #pragma unroll
    for (int j = 0; j < 8; ++j) v[j] = *(const i32x4*)(ap + it * 2048 + j * 4);
    u32 m = 0;
    #pragma unroll
    for (int j = 0; j < 8; ++j){
      m |= ((u32)v[j][0] << (4*j))   | ((u32)v[j][1] << (4*j+1))
         | ((u32)v[j][2] << (4*j+2)) | ((u32)v[j][3] << (4*j+3));
    }
    bp[it * 64] = m;
  }
}

// ---------- K3: bitmask-sourced binary GEMM. 4 waves x 64 feats, 64 rows, split-K=4 ----------
// grid 512 (2/CU): xcd=bid&7 -> half=xcd&1 (top/bottom), chunk c=xcd>>1; slot=bid>>3.
// Block: 64 rows x 256 feats x 2048 K = 8 phases of 256 K. NO HBM loads in the loop:
// bm window (L2) expanded in VALU -> LDS; B (L2) in ping-pong regs; adj traffic = 0.
// Thread t: rows {q*4 + (t>>6)}, k-slot 4*(t&63)..+3 (nibble of one bm word).
__global__ __launch_bounds__(256, 2) void k3_main(const u32* __restrict__ bm,
    const u16* __restrict__ outF, const u16* __restrict__ pbf,
    float* __restrict__ P, float* __restrict__ pd){
  __shared__ u16 AbS[2][16768];   // [buf][16 slices x 1048 u16] (padded) = 67,072 B
  __shared__ u32 plS[1024];       // chunk's 2048 p values as bf16-pairs
  const int bid = blockIdx.x;
  const int xcd = bid & 7, slot = bid >> 3;
  const int half = xcd & 1, c = xcd >> 1;
  const int tile = half * 64 + slot;       // 0..127 ; <64 top
  const bool top = half == 0;
  const int i0 = tile * 64;
  const int kbase = c * 2048;
  const int pb = tile * 4 + c;
  const int tid = threadIdx.x, l = tid & 63, w4 = tid >> 6;
  const int r = l & 31, h = l >> 5;
  const u16* bq0 = outF + (size_t)c * 524288 + (w4 * 64 + r) * 16 + h * 8;
  const u32* bmq = bm + (size_t)(i0 + w4) * 256 + (kbase >> 5) + (l >> 3);
  u16* const wp0 = &AbS[0][0] + (l >> 2) * 1048 + ((l >> 1) & 1) * 512 + 4 * (l & 1);
  const u16* const rp0 = &AbS[0][0] + h * 512 + r * 8;
  const int sh4 = 4 * (l & 7);

  // stage p (chunk covers K [kbase,+2048); p period 4096 -> half (c&1))
  if (top){
    plS[tid] = 0x3F803F80u; plS[tid + 256] = 0x3F803F80u;
    plS[tid + 512] = 0x3F803F80u; plS[tid + 768] = 0x3F803F80u;
  } else {
    const u32* ps = (const u32*)pbf + (c & 1) * 1024;
    plS[tid] = ps[tid]; plS[tid + 256] = ps[tid + 256];
    plS[tid + 512] = ps[tid + 512]; plS[tid + 768] = ps[tid + 768];
  }
  __syncthreads();

  u32 bmr[16];
  bf16x8 BA[8], BB[8];
  f32x16 a00 = {}, a01 = {}, a10 = {}, a11 = {};
  float dd[16] = {0.f,0.f,0.f,0.f,0.f,0.f,0.f,0.f,0.f,0.f,0.f,0.f,0.f,0.f,0.f,0.f};

#define BM_LOAD(T_) { _Pragma("unroll") for (int q_ = 0; q_ < 16; ++q_) \
    bmr[q_] = bmq[(size_t)q_ * 1024 + (T_) * 8]; \
  asm volatile("" ::: "memory"); }

#define B_ISS(B_,G_) { const u16* bb_ = bq0 + (size_t)(G_) * 4096; \
  _Pragma("unroll") for (int j_ = 0; j_ < 4; ++j_){ \
    B_[2*j_]   = *(const bf16x8*)(bb_ + j_ * 4096); \
    B_[2*j_+1] = *(const bf16x8*)(bb_ + j_ * 4096 + 512); } \
  asm volatile("" ::: "memory"); }

#define MFMA4(B_,BUF_,S0_) { \
  const u16* rb_ = rp0 + (BUF_) * 16768 + (S0_) * 1048; \
  __builtin_amdgcn_s_setprio(1); \
  _Pragma("unroll") for (int j_ = 0; j_ < 4; ++j_){ \
    bf16x8 a0_ = *(const bf16x8*)(rb_ + j_ * 1048); \
    bf16x8 a1_ = *(const bf16x8*)(rb_ + j_ * 1048 + 256); \
    a00 = __builtin_amdgcn_mfma_f32_32x32x16_bf16(a0_, B_[2*j_],   a00, 0, 0, 0); \
    a01 = __builtin_amdgcn_mfma_f32_32x32x16_bf16(a0_, B_[2*j_+1], a01, 0, 0, 0); \
    a10 = __builtin_amdgcn_mfma_f32_32x32x16_bf16(a1_, B_[2*j_],   a10, 0, 0, 0); \
    a11 = __builtin_amdgcn_mfma_f32_32x32x16_bf16(a1_, B_[2*j_+1], a11, 0, 0, 0); } \
  __builtin_amdgcn_s_setprio(0); }

#define PACK(T_,BUF_) { \
  u32 p0_ = plS[(T_) * 128 + 2 * l]; \
  u32 p1_ = plS[(T_) * 128 + 2 * l + 1]; \
  _Pragma("unroll") for (int q_ = 0; q_ < 16; ++q_){ \
    u32 e_ = (bmr[q_] >> sh4) & 0xFu; \
    u32 w0_ = (((u32)-(int)(e_ & 1u)) & 0xFFFFu) | (((u32)-(int)((e_>>1)&1u)) & 0xFFFF0000u); \
    u32 w1_ = (((u32)-(int)((e_>>2)&1u)) & 0xFFFFu) | (((u32)-(int)((e_>>3)&1u)) & 0xFFFF0000u); \
    w0_ &= p0_; w1_ &= p1_; \
    dd[q_] += __uint_as_float(w0_ << 16) + __uint_as_float(w0_ & 0xFFFF0000u) \
            + __uint_as_float(w1_ << 16) + __uint_as_float(w1_ & 0xFFFF0000u); \
    uint2 wv_; wv_.x = w0_; wv_.y = w1_; \
    *(uint2*)(wp0 + (BUF_) * 16768 + (q_ * 4 + w4) * 8) = wv_; } }

#define KBAR() { asm volatile("s_waitcnt lgkmcnt(0)" ::: "memory"); \
  __builtin_amdgcn_s_barrier(); asm volatile("" ::: "memory"); }

  // prologue: bm(ph0) -> pack buf0; B slices 0..3
  BM_LOAD(0);
  B_ISS(BA, 0);
  PACK(0, 0);
  KBAR();

  #pragma unroll 1
  for (int t = 0; t < 8; ++t){
    const int buf = t & 1;
    const int g0 = t * 16;
    // sub0
    B_ISS(BB, g0 + 4);
    if (t < 7) BM_LOAD(t + 1);
    MFMA4(BA, buf, 0);
    // sub1
    B_ISS(BA, g0 + 8);
    MFMA4(BB, buf, 4);
    // sub2
    B_ISS(BB, g0 + 12);
    MFMA4(BA, buf, 8);
    // sub3
    if (t < 7){ B_ISS(BA, g0 + 16); }
    MFMA4(BB, buf, 12);
    if (t < 7){
      PACK(t + 1, buf ^ 1);
      KBAR();
    }
  }

#undef BM_LOAD
#undef B_ISS
#undef MFMA4
#undef PACK
#undef KBAR

  // ---- epilogue: per-row d via wave shfl-reduce; P partial store ----
  #pragma unroll
  for (int q = 0; q < 16; ++q){
    float v = dd[q];
    #pragma unroll
    for (int mk = 1; mk < 64; mk <<= 1) v += __shfl_xor(v, mk);
    if (l == 0) pd[(size_t)pb * 64 + q * 4 + w4] = v;
  }
  float* Pb = P + (size_t)pb * 16384 + w4 * 64 + r;
  #pragma unroll
  for (int e = 0; e < 16; ++e){
    int rr = (e & 3) + 8 * (e >> 2) + 4 * h;
    __builtin_nontemporal_store(a00[e], Pb + (size_t)rr * 256);
    __builtin_nontemporal_store(a01[e], Pb + (size_t)rr * 256 + 32);
    __builtin_nontemporal_store(a10[e], Pb + (size_t)(rr + 32) * 256);
    __builtin_nontemporal_store(a11[e], Pb + (size_t)(rr + 32) * 256 + 32);
  }
}

// ---------- K4: combine 4 K-split partials + softmax coeffs + sigmoid ----------
__global__ void k4_final(const float* __restrict__ P, const float* __restrict__ pd,
    const float* __restrict__ v0, const float* __restrict__ v1, float* __restrict__ out){
  const int i = blockIdx.x, n = threadIdx.x;
  const int tile = i >> 6, rloc = i & 63;
  const size_t base = ((size_t)tile * 4 * 64 + rloc) * 256 + n;
  float P0 = __builtin_nontemporal_load(P + base);
  float P1 = __builtin_nontemporal_load(P + base + 16384);
  float P2 = __builtin_nontemporal_load(P + base + 32768);
  float P3 = __builtin_nontemporal_load(P + base + 49152);
  const float* pdp = pd + (size_t)tile * 256 + rloc;
  float d0 = pdp[0], d1 = pdp[64], d2 = pdp[128], d3 = pdp[192];
  float val;
  if (i < 4096){
    // top rows: chunks 0,1 cover K<4096 (coef e0), chunks 2,3 cover K>=4096 (coef e1)
    float va = v0[i], vb = v1[i];
    float m = fmaxf(va, vb);
    float e0 = __expf(va - m), e1 = __expf(vb - m);
    val = (e0 * (P0 + P1) + e1 * (P2 + P3)) / (e0 * (d0 + d1) + e1 * (d2 + d3));
  } else {
    val = (P0 + P1 + P2 + P3) / (d0 + d1 + d2 + d3);
  }
  out[(size_t)i * 256 + n] = 1.0f / (1.0f + __expf(-val));
}

extern "C" void kernel_launch(void* const* d_in, const int* in_sizes, int n_in,
                              void* d_out, int out_size, void* d_ws, size_t ws_size,
                              hipStream_t stream)
{
  const float* x      = (const float*)d_in[0];
  const float* weight = (const float*)d_in[1];
  const float* av     = (const float*)d_in[2];
  const int*   adj    = (const int*)d_in[3];
  float* out = (float*)d_out;
  char* ws = (char*)d_ws;
  float* P     = (float*)(ws + 0);             // 33,554,432 B
  float* pd    = (float*)(ws + 33554432);      //    131,072 B
  u16*   outF  = (u16*)  (ws + 33685504);      //  4,194,304 B
  u16*   wT    = (u16*)  (ws + 37879808);      //    262,144 B
  u16*   pbf   = (u16*)  (ws + 38141952);      //      8,192 B
  float* v0    = (float*)(ws + 38150144);      //     16,384 B
  float* v1    = (float*)(ws + 38166528);      //     16,384 B
  u32*   bm    = (u32*)  (ws + 38182912);      //  8,388,608 B

  k0_wt   <<<512, 256, 0, stream>>>(weight, wT);
  k2bm    <<<2048, 256, 0, stream>>>(adj, bm);
  k1_gemm <<<256, 512, 0, stream>>>(x, wT, av, outF, v0, v1, pbf);
  k3_main <<<512, 256, 0, stream>>>(bm, outF, pbf, P, pd);
  k4_final<<<8192, 256, 0, stream>>>(P, pd, v0, v1, out);
}

// Round 15
// 105.307 us; speedup vs baseline: 1.3097x; 1.3097x over previous
//
#include <hip/hip_runtime.h>

using u32 = unsigned int;
using u16 = unsigned short;

typedef __attribute__((ext_vector_type(8)))  __bf16 bf16x8;
typedef __attribute__((ext_vector_type(16))) float  f32x16;
typedef __attribute__((ext_vector_type(4)))  float  f32x4;
typedef __attribute__((ext_vector_type(4)))  int    i32x4;

__device__ __forceinline__ u32 f2bf(float f){
  u32 u = __float_as_uint(f);
  return (u + 0x7FFFu + ((u >> 16) & 1u)) >> 16;
}
__device__ __forceinline__ u32 pack2bf(float lo, float hi){
  return f2bf(lo) | (f2bf(hi) << 16);
}
__device__ __forceinline__ float bfu2f(u32 us){ return __uint_as_float(us << 16); }
__device__ __forceinline__ float lrelu(float x){ return x > 0.f ? x : 0.01f * x; }

// ---------- K0: weight [512][256] f32 -> wT [256][512] bf16 ----------
__global__ void k0_wt(const float* __restrict__ w, u16* __restrict__ wT){
  int u = blockIdx.x * 256 + threadIdx.x;
  int k = u >> 8, n = u & 255;
  wT[(size_t)n * 512 + k] = (u16)f2bf(w[(size_t)k * 256 + n]);
}

// ---------- K1: out = x@W -> outF (MFMA-frag layout) + v0/v1 + p(bf16) ----------
__global__ __launch_bounds__(512, 2) void k1_gemm(const float* __restrict__ x,
    const u16* __restrict__ wT, const float* __restrict__ av, u16* __restrict__ outF,
    float* __restrict__ v0, float* __restrict__ v1, u16* __restrict__ pbf){
  __shared__ float tb[8][32][36];
  __shared__ float afl[512];
  __shared__ float sred[2][32][17];
  __shared__ float srw[2][32];
  const int i0 = blockIdx.x * 32;
  const int tid = threadIdx.x;
  const int lane = tid & 63, wv = tid >> 6;
  const int r = lane & 31, h = lane >> 5;
  const float* xp = x + (size_t)(i0 + r) * 512 + h * 8;
  const u16*   bp = wT + (size_t)(wv * 32 + r) * 512 + h * 8;
  f32x16 acc = {};
  for (int s = 0; s < 32; ++s){
    f32x4 a0 = *(const f32x4*)xp;
    f32x4 a1 = *(const f32x4*)(xp + 4);
    i32x4 pk = { (int)pack2bf(a0[0], a0[1]), (int)pack2bf(a0[2], a0[3]),
                 (int)pack2bf(a1[0], a1[1]), (int)pack2bf(a1[2], a1[3]) };
    bf16x8 af = __builtin_bit_cast(bf16x8, pk);
    bf16x8 bf = *(const bf16x8*)bp;
    acc = __builtin_amdgcn_mfma_f32_32x32x16_bf16(af, bf, acc, 0, 0, 0);
    xp += 16; bp += 16;
  }
  #pragma unroll
  for (int re = 0; re < 16; ++re){
    int rr = (re & 3) + 8 * (re >> 2) + 4 * h;
    tb[wv][r][rr] = acc[re];
  }
  afl[tid] = av[tid];
  __syncthreads();
  {
    const int n2 = lane >> 1, ic = (lane & 1) * 16;
    const float* tp = &tb[wv][n2][ic];
    i32x4 w0 = { (int)pack2bf(tp[0],tp[1]),   (int)pack2bf(tp[2],tp[3]),
                 (int)pack2bf(tp[4],tp[5]),   (int)pack2bf(tp[6],tp[7]) };
    i32x4 w1 = { (int)pack2bf(tp[8],tp[9]),   (int)pack2bf(tp[10],tp[11]),
                 (int)pack2bf(tp[12],tp[13]), (int)pack2bf(tp[14],tp[15]) };
    const int n = wv * 32 + n2;
    const int k16 = (i0 + ic) >> 4;
    u16* op = outF + ((size_t)k16 * 256 + n) * 16;
    *(i32x4*)op = w0;
    *((i32x4*)op + 1) = w1;
  }
  const int row = tid & 31, g = tid >> 5;
  const int w8 = g >> 1, fh = (g & 1) * 16;
  float a1c = 0.f, a2c = 0.f;
  #pragma unroll
  for (int f = 0; f < 16; ++f){
    float tv = tb[w8][fh + f][row];
    a1c = fmaf(tv, afl[w8 * 32 + fh + f], a1c);
    a2c = fmaf(tv, afl[256 + w8 * 32 + fh + f], a2c);
  }
  sred[0][row][g] = a1c; sred[1][row][g] = a2c;
  __syncthreads();
  if (tid < 64){
    int which = tid >> 5, r2 = tid & 31;
    float s = 0.f;
    #pragma unroll
    for (int g2 = 0; g2 < 16; ++g2) s += sred[which][r2][g2];
    srw[which][r2] = s;
  }
  __syncthreads();
  if (tid < 16){
    int k = (i0 >> 1) + tid;
    float sa  = srw[0][2*tid],   sb  = srw[1][2*tid];
    float sa1 = srw[0][2*tid+1], sb1 = srw[1][2*tid+1];
    v0[k] = lrelu(sa + sb);
    v1[k] = lrelu(sa1 + sb1);
    float w = lrelu(sa + sb1);
    pbf[k] = (u16)f2bf(__expf(w));
  }
}

// ---------- K3: wave-specialized binary GEMM (producer/consumer) ----------
// grid 256 (1 block/CU): xcd=bid&7 -> half=xcd&1, chunk c=(xcd>>1)&1, hi=xcd>>2.
// Block: 512 thr = 8 waves. Waves 0-3 PRODUCE: stream adj (1KB-contiguous row
// loads), pack mask&p -> LDS A (double-buffered), accumulate d. Waves 4-7 CONSUME:
// B ping-pong (L2) + MFMA from LDS. Producer vmem queue = adj ONLY; consumer = B
// ONLY -> in-order vmcnt retirement never couples HBM latency into the MFMA path.
// Tile 64 rows x 256 feats x K-chunk 4096 = 16 phases of 256 K; 1 barrier/phase.
__global__ __launch_bounds__(512, 1) void k3_main(const int* __restrict__ adj,
    const u16* __restrict__ outF, const u16* __restrict__ pbf,
    float* __restrict__ P, float* __restrict__ pd){
  __shared__ u16 AbS[2][16768];   // [buf][16 slices x 1048 u16 padded] = 67,072 B
  __shared__ u32 plS[2048];       // full-period p as bf16-pairs (8 KB)
  const int bid = blockIdx.x;
  const int xcd = bid & 7, grp = bid >> 3;      // grp 0..31
  const int half = xcd & 1, c = (xcd >> 1) & 1, hi = xcd >> 2;
  const int tile = half * 64 + hi * 32 + grp;   // 0..127 ; <64 top
  const bool top = (half == 0);
  const int i0 = tile * 64;
  const int kbase = c * 4096;
  const int pb = tile * 2 + c;
  const int tid = threadIdx.x, l = tid & 63, w = tid >> 6;
  const int r = l & 31, h = l >> 5;
  const bool isProd = (w < 4);
  const int w4 = w & 3;

  // stage p (p has period 4096 -> same table for both chunks; top = 1.0)
  if (top){
    plS[tid] = 0x3F803F80u;        plS[tid + 512] = 0x3F803F80u;
    plS[tid + 1024] = 0x3F803F80u; plS[tid + 1536] = 0x3F803F80u;
  } else {
    const u32* ps = (const u32*)pbf;
    plS[tid] = ps[tid];             plS[tid + 512] = ps[tid + 512];
    plS[tid + 1024] = ps[tid + 1024]; plS[tid + 1536] = ps[tid + 1536];
  }
  __syncthreads();

  // producer state: rows w4*16..+15, lane covers k-slots 4l..4l+3 of each phase
  const int* aq0 = adj + (size_t)(i0 + w4 * 16) * 8192 + kbase + l * 4;
  u16* const wp0 = &AbS[0][0] + (l >> 2) * 1048 + ((l >> 1) & 1) * 512
                   + 4 * (l & 1) + w4 * 128;
  // consumer state: feats fb..fb+63
  const int fb = w4 * 64;
  const u16* bq0 = outF + (size_t)c * 1048576 + (fb + r) * 16 + h * 8;

  i32x4 ar[16];
  float dd[16] = {0.f,0.f,0.f,0.f,0.f,0.f,0.f,0.f,0.f,0.f,0.f,0.f,0.f,0.f,0.f,0.f};
  bf16x8 BA[8], BB[8];
  f32x16 a00 = {}, a01 = {}, a10 = {}, a11 = {};

#define ISSUE(T_) { _Pragma("unroll") for (int j_ = 0; j_ < 16; ++j_) \
    ar[j_] = *(const i32x4*)(aq0 + (size_t)j_ * 8192 + (T_) * 256); \
  asm volatile("" ::: "memory"); }

#define BFS(W_) (__uint_as_float((W_) << 16) + __uint_as_float((W_) & 0xFFFF0000u))

#define PACKALL(T_,BUF_) { \
  u32 pp0_ = plS[(T_) * 128 + 2 * l]; \
  u32 pp1_ = plS[(T_) * 128 + 2 * l + 1]; \
  u16* wb_ = wp0 + (BUF_) * 16768; \
  _Pragma("unroll") for (int j_ = 0; j_ < 16; ++j_){ \
    i32x4 a_ = ar[j_]; \
    u32 w0_ = ((((u32)(-a_[0])) & 0xFFFFu) | (((u32)(-a_[1])) << 16)) & pp0_; \
    u32 w1_ = ((((u32)(-a_[2])) & 0xFFFFu) | (((u32)(-a_[3])) << 16)) & pp1_; \
    dd[j_] += BFS(w0_) + BFS(w1_); \
    uint2 wv_; wv_.x = w0_; wv_.y = w1_; \
    *(uint2*)(wb_ + j_ * 8) = wv_; } }

#define B_ISS(B_,G_) { const u16* bb_ = bq0 + (size_t)(G_) * 4096; \
  _Pragma("unroll") for (int j_ = 0; j_ < 4; ++j_){ \
    B_[2*j_]   = *(const bf16x8*)(bb_ + j_ * 4096); \
    B_[2*j_+1] = *(const bf16x8*)(bb_ + j_ * 4096 + 512); } \
  asm volatile("" ::: "memory"); }

#define MFMA4(B_,BUF_,S0_) { \
  const u16* rb_ = &AbS[0][0] + (BUF_) * 16768 + (S0_) * 1048 + h * 512 + r * 8; \
  __builtin_amdgcn_s_setprio(1); \
  _Pragma("unroll") for (int j_ = 0; j_ < 4; ++j_){ \
    bf16x8 a0_ = *(const bf16x8*)(rb_ + j_ * 1048); \
    bf16x8 a1_ = *(const bf16x8*)(rb_ + j_ * 1048 + 256); \
    a00 = __builtin_amdgcn_mfma_f32_32x32x16_bf16(a0_, B_[2*j_],   a00, 0, 0, 0); \
    a01 = __builtin_amdgcn_mfma_f32_32x32x16_bf16(a0_, B_[2*j_+1], a01, 0, 0, 0); \
    a10 = __builtin_amdgcn_mfma_f32_32x32x16_bf16(a1_, B_[2*j_],   a10, 0, 0, 0); \
    a11 = __builtin_amdgcn_mfma_f32_32x32x16_bf16(a1_, B_[2*j_+1], a11, 0, 0, 0); } \
  __builtin_amdgcn_s_setprio(0); }

#define KBAR() { asm volatile("s_waitcnt lgkmcnt(0)" ::: "memory"); \
  __builtin_amdgcn_s_barrier(); asm volatile("" ::: "memory"); }

  if (isProd){ ISSUE(0); } else { B_ISS(BA, 0); }
  #pragma unroll 1
  for (int t = 0; t <= 16; ++t){
    if (isProd){
      if (t < 16){
        PACKALL(t, t & 1);
        if (t < 15) ISSUE(t + 1);
      }
    } else {
      if (t >= 1){
        const int ph = t - 1, buf = ph & 1, g0 = ph * 16;
        B_ISS(BB, g0 + 4);  MFMA4(BA, buf, 0);
        B_ISS(BA, g0 + 8);  MFMA4(BB, buf, 4);
        B_ISS(BB, g0 + 12); MFMA4(BA, buf, 8);
        if (ph < 15){ B_ISS(BA, g0 + 16); }
        MFMA4(BB, buf, 12);
      }
    }
    KBAR();
  }

#undef ISSUE
#undef PACKALL
#undef B_ISS
#undef MFMA4
#undef KBAR
#undef BFS

  if (isProd){
    #pragma unroll
    for (int j = 0; j < 16; ++j){
      float v = dd[j];
      #pragma unroll
      for (int mk = 1; mk < 64; mk <<= 1) v += __shfl_xor(v, mk);
      if (l == 0) pd[(size_t)pb * 64 + w4 * 16 + j] = v;
    }
  } else {
    float* Pb = P + (size_t)pb * 16384 + fb + r;
    #pragma unroll
    for (int e = 0; e < 16; ++e){
      int rr = (e & 3) + 8 * (e >> 2) + 4 * h;
      __builtin_nontemporal_store(a00[e], Pb + (size_t)rr * 256);
      __builtin_nontemporal_store(a01[e], Pb + (size_t)rr * 256 + 32);
      __builtin_nontemporal_store(a10[e], Pb + (size_t)(rr + 32) * 256);
      __builtin_nontemporal_store(a11[e], Pb + (size_t)(rr + 32) * 256 + 32);
    }
  }
}

// ---------- K4: combine split-K=2 partials + softmax coeffs + sigmoid ----------
__global__ void k4_final(const float* __restrict__ P, const float* __restrict__ pd,
    const float* __restrict__ v0, const float* __restrict__ v1, float* __restrict__ out){
  const int i = blockIdx.x, n = threadIdx.x;
  const int tile = i >> 6, rloc = i & 63;
  const size_t base = (size_t)(tile * 2) * 16384 + (size_t)rloc * 256 + n;
  float P0 = __builtin_nontemporal_load(P + base);
  float P1 = __builtin_nontemporal_load(P + base + 16384);
  float d0 = pd[tile * 128 + rloc];
  float d1 = pd[tile * 128 + 64 + rloc];
  float val;
  if (i < 4096){
    // chunk 0 covers K<4096 (coef e0), chunk 1 covers K>=4096 (coef e1)
    float va = v0[i], vb = v1[i];
    float m = fmaxf(va, vb);
    float e0 = __expf(va - m), e1 = __expf(vb - m);
    val = (e0 * P0 + e1 * P1) / (e0 * d0 + e1 * d1);
  } else {
    val = (P0 + P1) / (d0 + d1);
  }
  out[(size_t)i * 256 + n] = 1.0f / (1.0f + __expf(-val));
}

extern "C" void kernel_launch(void* const* d_in, const int* in_sizes, int n_in,
                              void* d_out, int out_size, void* d_ws, size_t ws_size,
                              hipStream_t stream)
{
  const float* x      = (const float*)d_in[0];
  const float* weight = (const float*)d_in[1];
  const float* av     = (const float*)d_in[2];
  const int*   adj    = (const int*)d_in[3];
  float* out = (float*)d_out;
  char* ws = (char*)d_ws;
  float* P     = (float*)(ws + 0);             // 16,777,216 B
  float* pd    = (float*)(ws + 16777216);      //     65,536 B
  u16*   outF  = (u16*)  (ws + 16842752);      //  4,194,304 B
  u16*   wT    = (u16*)  (ws + 21037056);      //    262,144 B
  u16*   pbf   = (u16*)  (ws + 21299200);      //      8,192 B
  float* v0    = (float*)(ws + 21307392);      //     16,384 B
  float* v1    = (float*)(ws + 21323776);      //     16,384 B

  k0_wt   <<<512, 256, 0, stream>>>(weight, wT);
  k1_gemm <<<256, 512, 0, stream>>>(x, wT, av, outF, v0, v1, pbf);
  k3_main <<<256, 512, 0, stream>>>(adj, outF, pbf, P, pd);
  k4_final<<<8192, 256, 0, stream>>>(P, pd, v0, v1, out);
}